// Round 1
// baseline (801.210 us; speedup 1.0000x reference)
//
#include <hip/hip_runtime.h>

#define CHN 256
#define B_  16
#define N_  4096   // H*W
#define M_  1024   // pooled
#define CF  32     // C/8
#define CH2 128    // C/2

// ---------------- Kernel 1: projections f, g(pooled), hT(pooled, transposed) ----------------
struct K1A { float xs[64][128]; float ws2[64][196]; };            // 32768 + 50176 = 82944 B
struct K1B { float pools[160][128]; float poolh[32][132]; };      // 81920 + 16896 = 98816 B
union  K1U { K1A a; K1B b; };

__global__ __launch_bounds__(512, 1)
void k1_proj(const float* __restrict__ x, const float* __restrict__ wf,
             const float* __restrict__ wg, const float* __restrict__ wh,
             float* __restrict__ f, float* __restrict__ g, float* __restrict__ hT) {
    __shared__ K1U sm;
    const int t  = threadIdx.x;
    const int b  = blockIdx.x >> 5;     // 16 batches
    const int r2 = blockIdx.x & 31;     // 32 row-pairs
    const int nb = r2 * 128;            // 2 rows of 64 = 128 contiguous positions
    const int mb = r2 * 32;             // pooled base

    const int pg = t & 31;              // position quad group
    const int og = t >> 5;              // 0..15 output groups of 12
    const int p0 = pg * 4;
    const int o0 = og * 12;

    float acc[12][4];
#pragma unroll
    for (int j = 0; j < 12; ++j)
#pragma unroll
        for (int i = 0; i < 4; ++i) acc[j][i] = 0.f;

    const int ccs = t & 63;
    const int og8 = t >> 6;             // 0..7

    for (int ch = 0; ch < 4; ++ch) {
        const int c0 = ch * 64;
        // stage x tile: xs[cc][pos]
        {
            const int pos4 = t & 31;
            const int ccx  = t >> 5;    // 0..15
#pragma unroll
            for (int r = 0; r < 4; ++r) {
                const int cc = ccx + r * 16;
                const float4 v = *(const float4*)&x[((size_t)(b * CHN + c0 + cc)) * N_ + nb + pos4 * 4];
                *(float4*)&sm.a.xs[cc][pos4 * 4] = v;
            }
        }
        // stage stacked weights transposed: ws2[cc][o], o in [0,192)
        {
#pragma unroll
            for (int j = 0; j < 24; ++j) {
                const int o = og8 * 24 + j;
                const float* wrow = (o < 32) ? (wf + (size_t)o * CHN)
                                  : (o < 64) ? (wg + (size_t)(o - 32) * CHN)
                                             : (wh + (size_t)(o - 64) * CHN);
                sm.a.ws2[ccs][o] = wrow[c0 + ccs];
            }
        }
        __syncthreads();
#pragma unroll 4
        for (int cc = 0; cc < 64; ++cc) {
            const float4 xv = *(const float4*)&sm.a.xs[cc][p0];
            const float4 w0 = *(const float4*)&sm.a.ws2[cc][o0];
            const float4 w1 = *(const float4*)&sm.a.ws2[cc][o0 + 4];
            const float4 w2 = *(const float4*)&sm.a.ws2[cc][o0 + 8];
            const float wv[12] = {w0.x,w0.y,w0.z,w0.w, w1.x,w1.y,w1.z,w1.w, w2.x,w2.y,w2.z,w2.w};
            const float xvv[4] = {xv.x, xv.y, xv.z, xv.w};
#pragma unroll
            for (int j = 0; j < 12; ++j)
#pragma unroll
                for (int i = 0; i < 4; ++i)
                    acc[j][i] += wv[j] * xvv[i];
        }
        __syncthreads();
    }

    // f rows (o < 32) go straight to global
#pragma unroll
    for (int j = 0; j < 12; ++j) {
        const int o = o0 + j;
        if (o < 32) {
            *(float4*)&f[((size_t)(b * CF + o)) * N_ + nb + p0] =
                make_float4(acc[j][0], acc[j][1], acc[j][2], acc[j][3]);
        }
    }
    __syncthreads();   // before aliasing pools over xs/ws2
#pragma unroll
    for (int j = 0; j < 12; ++j) {
        const int o = o0 + j;
        if (o >= 32) {
            *(float4*)&sm.b.pools[o - 32][p0] =
                make_float4(acc[j][0], acc[j][1], acc[j][2], acc[j][3]);
        }
    }
    __syncthreads();
    // 2x2 maxpool: rows (2*r2, 2*r2+1) x cols (2j, 2j+1)
    {
        const int jj  = t & 31;
        const int o2b = t >> 5;         // 0..15
#pragma unroll
        for (int k = 0; k < 10; ++k) {
            const int o2 = o2b + k * 16;     // 0..159
            const float v0 = sm.b.pools[o2][2 * jj];
            const float v1 = sm.b.pools[o2][2 * jj + 1];
            const float v2 = sm.b.pools[o2][64 + 2 * jj];
            const float v3 = sm.b.pools[o2][64 + 2 * jj + 1];
            const float mx = fmaxf(fmaxf(v0, v1), fmaxf(v2, v3));
            if (o2 < 32) {
                g[((size_t)(b * CF + o2)) * M_ + mb + jj] = mx;
            } else {
                sm.b.poolh[jj][o2 - 32] = mx;
            }
        }
    }
    __syncthreads();
    // store hT[b][m][c] coalesced
    {
#pragma unroll
        for (int k = 0; k < 2; ++k) {
            const int idx = t + k * 512;      // 0..1023 float4s
            const int row = idx >> 5;         // 0..31
            const int cq  = idx & 31;         // 0..31 -> c = cq*4
            const float4 v = *(const float4*)&sm.b.poolh[row][cq * 4];
            *(float4*)&hT[((size_t)(b * M_ + mb + row)) * CH2 + cq * 4] = v;
        }
    }
}

// ---------------- Kernel 2: fused attention + wo projection + residual ----------------
struct K2A {
    float fs[32][64];
    float gs[32][128];
    float ss[128][64];     // S^T then P^T, [m][n]
    float red[4][64];
    float redsum[4][64];
    float Mrow[64];
    float Lrow[64];
    float Rrow[64];
};
struct K2B { float Olds[128][72]; float wos[128][36]; };
union  K2U { K2A a; K2B b; };

__global__ __launch_bounds__(256, 2)
void k2_attn(const float* __restrict__ f, const float* __restrict__ g,
             const float* __restrict__ hT, const float* __restrict__ wo,
             const float* __restrict__ x, const float* __restrict__ gam,
             float* __restrict__ out) {
    __shared__ K2U sm;
    const int t  = threadIdx.x;
    const int b  = blockIdx.x >> 6;     // 16 batches
    const int nt = blockIdx.x & 63;     // 64 n-tiles
    const int n0 = nt * 64;

    const int tn = t & 15, tm = t >> 4;     // phase A: 4n x 8m tile
    const int tcn = t & 15, tcc = t >> 4;   // phase C: 4n x 8c tile

    float acc[4][8];
#pragma unroll
    for (int i = 0; i < 4; ++i)
#pragma unroll
        for (int j = 0; j < 8; ++j) acc[i][j] = 0.f;

    // stage f tile [32][64]
#pragma unroll
    for (int r = 0; r < 8; ++r) {
        const int idx = t + r * 256;
        const int k = idx >> 6, n = idx & 63;
        sm.a.fs[k][n] = f[((size_t)(b * CF + k)) * N_ + n0 + n];
    }
    if (t < 64) { sm.a.Mrow[t] = -1e30f; sm.a.Lrow[t] = 0.f; }
    __syncthreads();

    for (int mt = 0; mt < 8; ++mt) {
        const int m0 = mt * 128;
        // stage g tile [32][128]
#pragma unroll
        for (int r = 0; r < 16; ++r) {
            const int idx = t + r * 256;
            const int k = idx >> 7, m = idx & 127;
            sm.a.gs[k][m] = g[((size_t)(b * CF + k)) * M_ + m0 + m];
        }
        __syncthreads();
        // phase A: S^T[m][n] = sum_k f[k][n]*g[k][m]
        {
            float s[8][4];
#pragma unroll
            for (int mj = 0; mj < 8; ++mj)
#pragma unroll
                for (int i = 0; i < 4; ++i) s[mj][i] = 0.f;
#pragma unroll 8
            for (int k = 0; k < 32; ++k) {
                const float4 fv = *(const float4*)&sm.a.fs[k][tn * 4];
                const float4 g0 = *(const float4*)&sm.a.gs[k][tm * 8];
                const float4 g1 = *(const float4*)&sm.a.gs[k][tm * 8 + 4];
                const float fvv[4] = {fv.x, fv.y, fv.z, fv.w};
                const float gvv[8] = {g0.x,g0.y,g0.z,g0.w, g1.x,g1.y,g1.z,g1.w};
#pragma unroll
                for (int mj = 0; mj < 8; ++mj)
#pragma unroll
                    for (int i = 0; i < 4; ++i)
                        s[mj][i] += gvv[mj] * fvv[i];
            }
#pragma unroll
            for (int mj = 0; mj < 8; ++mj)
                *(float4*)&sm.a.ss[tm * 8 + mj][tn * 4] =
                    make_float4(s[mj][0], s[mj][1], s[mj][2], s[mj][3]);
        }
        __syncthreads();
        // B1: partial row-max
        {
            const int n = t & 63, q = t >> 6;
            float pm = -1e30f;
#pragma unroll 8
            for (int mm = 0; mm < 32; ++mm) pm = fmaxf(pm, sm.a.ss[q * 32 + mm][n]);
            sm.a.red[q][n] = pm;
        }
        __syncthreads();
        if (t < 64) {
            const float m4 = fmaxf(fmaxf(sm.a.red[0][t], sm.a.red[1][t]),
                                   fmaxf(sm.a.red[2][t], sm.a.red[3][t]));
            const float Mo = sm.a.Mrow[t];
            const float Mn = fmaxf(Mo, m4);
            sm.a.Rrow[t] = __expf(Mo - Mn);
            sm.a.Mrow[t] = Mn;
        }
        __syncthreads();
        // B2: p = exp(s - M), partial row-sum, write back into ss
        {
            const int n = t & 63, q = t >> 6;
            const float Mn = sm.a.Mrow[n];
            float ls = 0.f;
#pragma unroll 8
            for (int mm = 0; mm < 32; ++mm) {
                const int m = q * 32 + mm;
                const float p = __expf(sm.a.ss[m][n] - Mn);
                sm.a.ss[m][n] = p;
                ls += p;
            }
            sm.a.redsum[q][n] = ls;
        }
        __syncthreads();
        if (t < 64) {
            sm.a.Lrow[t] = sm.a.Lrow[t] * sm.a.Rrow[t] +
                (sm.a.redsum[0][t] + sm.a.redsum[1][t] + sm.a.redsum[2][t] + sm.a.redsum[3][t]);
        }
        __syncthreads();
        // phase C: rescale acc, then acc += P^T h
        {
            float rr[4];
#pragma unroll
            for (int i = 0; i < 4; ++i) rr[i] = sm.a.Rrow[tcn * 4 + i];
#pragma unroll
            for (int i = 0; i < 4; ++i)
#pragma unroll
                for (int j = 0; j < 8; ++j) acc[i][j] *= rr[i];
            const float* hTb = hT + ((size_t)(b * M_ + m0)) * CH2 + tcc * 8;
#pragma unroll 2
            for (int m = 0; m < 128; ++m) {
                const float4 pv = *(const float4*)&sm.a.ss[m][tcn * 4];
                const float4 h0 = *(const float4*)&hTb[(size_t)m * CH2];
                const float4 h1 = *(const float4*)&hTb[(size_t)m * CH2 + 4];
                const float pvv[4] = {pv.x, pv.y, pv.z, pv.w};
                const float hv[8] = {h0.x,h0.y,h0.z,h0.w, h1.x,h1.y,h1.z,h1.w};
#pragma unroll
                for (int i = 0; i < 4; ++i)
#pragma unroll
                    for (int j = 0; j < 8; ++j)
                        acc[i][j] += pvv[i] * hv[j];
            }
        }
        __syncthreads();
    }

    // finalize: divide by L (read Lrow BEFORE union switch)
    {
        float invl[4];
#pragma unroll
        for (int i = 0; i < 4; ++i) invl[i] = 1.f / sm.a.Lrow[tcn * 4 + i];
#pragma unroll
        for (int i = 0; i < 4; ++i)
#pragma unroll
            for (int j = 0; j < 8; ++j) acc[i][j] *= invl[i];
    }
    __syncthreads();
    // write O^T to LDS: Olds[c][n]
#pragma unroll
    for (int j = 0; j < 8; ++j)
        *(float4*)&sm.b.Olds[tcc * 8 + j][tcn * 4] =
            make_float4(acc[0][j], acc[1][j], acc[2][j], acc[3][j]);

    const float gamma = gam[0];
    const int tn2 = t & 15, tc2 = t >> 4;
    for (int occ = 0; occ < 8; ++occ) {
        const int oc0 = occ * 32;
        __syncthreads();   // Olds visible / previous chunk readers done
        // stage wos[c][oc_local] for 32 oc
        {
            const int c = t & 127, ocr = t >> 7;   // ocr 0..1
#pragma unroll
            for (int j2 = 0; j2 < 16; ++j2) {
                const int ocl = ocr * 16 + j2;
                sm.b.wos[c][ocl] = wo[((size_t)(oc0 + ocl)) * CH2 + c];
            }
        }
        __syncthreads();
        float a2[2][4];
#pragma unroll
        for (int jj = 0; jj < 2; ++jj)
#pragma unroll
            for (int i = 0; i < 4; ++i) a2[jj][i] = 0.f;
#pragma unroll 4
        for (int k = 0; k < 128; ++k) {
            const float4 ov = *(const float4*)&sm.b.Olds[k][tn2 * 4];
            const float2 wv = *(const float2*)&sm.b.wos[k][tc2 * 2];
            a2[0][0] += wv.x * ov.x; a2[0][1] += wv.x * ov.y;
            a2[0][2] += wv.x * ov.z; a2[0][3] += wv.x * ov.w;
            a2[1][0] += wv.y * ov.x; a2[1][1] += wv.y * ov.y;
            a2[1][2] += wv.y * ov.z; a2[1][3] += wv.y * ov.w;
        }
#pragma unroll
        for (int jj = 0; jj < 2; ++jj) {
            const int oc = oc0 + tc2 * 2 + jj;
            const size_t base = ((size_t)(b * CHN + oc)) * N_ + n0 + tn2 * 4;
            const float4 xv = *(const float4*)&x[base];
            float4 r4;
            r4.x = gamma * a2[jj][0] + xv.x;
            r4.y = gamma * a2[jj][1] + xv.y;
            r4.z = gamma * a2[jj][2] + xv.z;
            r4.w = gamma * a2[jj][3] + xv.w;
            *(float4*)&out[base] = r4;
        }
    }
}

extern "C" void kernel_launch(void* const* d_in, const int* in_sizes, int n_in,
                              void* d_out, int out_size, void* d_ws, size_t ws_size,
                              hipStream_t stream) {
    (void)in_sizes; (void)n_in; (void)out_size; (void)ws_size;
    const float* x   = (const float*)d_in[0];
    const float* wf  = (const float*)d_in[1];
    const float* wg  = (const float*)d_in[2];
    const float* wh  = (const float*)d_in[3];
    const float* wo  = (const float*)d_in[4];
    const float* gam = (const float*)d_in[5];
    float* out = (float*)d_out;

    float* ws = (float*)d_ws;
    float* f  = ws;                     // B*32*4096  = 2,097,152 floats
    float* g  = ws + 2097152;           // B*32*1024  =   524,288 floats
    float* hT = ws + 2621440;           // B*1024*128 = 2,097,152 floats

    k1_proj<<<dim3(512), dim3(512), 0, stream>>>(x, wf, wg, wh, f, g, hT);
    k2_attn<<<dim3(1024), dim3(256), 0, stream>>>(f, g, hT, wo, x, gam, out);
}

// Round 4
// 230.597 us; speedup vs baseline: 3.4745x; 3.4745x over previous
//
#include <hip/hip_runtime.h>

#define N_  4096   // H*W
#define M_  1024   // pooled

typedef short bf16x8 __attribute__((ext_vector_type(8)));
typedef float f32x4  __attribute__((ext_vector_type(4)));

#define MFMA16(A,B,C) __builtin_amdgcn_mfma_f32_16x16x32_bf16(A,B,C,0,0,0)

__device__ __forceinline__ unsigned short f2b(float f){
    union { float f; unsigned u; } v; v.f = f;
    unsigned r = v.u + 0x7FFFu + ((v.u >> 16) & 1u);
    return (unsigned short)(r >> 16);
}
__device__ __forceinline__ unsigned packbf(float lo, float hi){
    return (unsigned)f2b(lo) | ((unsigned)f2b(hi) << 16);
}

// ---------------- k0: convert stacked weights wf|wg|wh -> bf16 ----------------
__global__ __launch_bounds__(256)
void k0_wcvt(const float* __restrict__ wf, const float* __restrict__ wg,
             const float* __restrict__ wh, short* __restrict__ wsB) {
    const int i4 = (blockIdx.x * 256 + threadIdx.x) * 4;    // 48 blocks -> 49152 elems
    const float* src = (i4 < 8192) ? (wf + i4) : (i4 < 16384) ? (wg + (i4 - 8192))
                                               : (wh + (i4 - 16384));
    float4 v = *(const float4*)src;
    uint2 o; o.x = packbf(v.x, v.y); o.y = packbf(v.z, v.w);
    *(uint2*)(wsB + i4) = o;
}

// ---------------- k1: MFMA projections + maxpool; emits fT, gT, hM (bf16) ------
// fT[b][n][32]  gT[b][m][32]  hM[b][c=128][m=1024]
__global__ __launch_bounds__(512, 2)
void k1_proj(const float* __restrict__ x, const short* __restrict__ wsB,
             const float* __restrict__ wo,
             short* __restrict__ fT, short* __restrict__ gT,
             short* __restrict__ hM, short* __restrict__ woB) {
    __shared__ __align__(64) char sm[65536];
    const int t    = threadIdx.x;
    const int b    = blockIdx.x >> 5;
    const int rp   = blockIdx.x & 31;
    const int nb   = rp * 128;
    const int mb   = rp * 32;
    const int lane = t & 63;
    const int w    = t >> 6;            // wave 0..7
    const int lr   = lane & 15, lg = lane >> 4;

    // ---- stage xs[n=128][c=256] bf16, XOR-swizzled, transposed from x ----
    {
        const int p   = t & 127;        // c-pair index: c = 2p, 2p+1
        const int seg = t >> 7;         // 0..3 -> n range seg*32..
        const float* xr0 = x + ((size_t)(b * 256 + 2 * p)) * N_ + nb + seg * 32;
        const float* xr1 = xr0 + N_;
#pragma unroll
        for (int jj = 0; jj < 32; jj += 4) {
            float4 a = *(const float4*)(xr0 + jj);
            float4 c = *(const float4*)(xr1 + jj);
            const float av[4] = {a.x, a.y, a.z, a.w};
            const float cv[4] = {c.x, c.y, c.z, c.w};
#pragma unroll
            for (int e = 0; e < 4; ++e) {
                const int n = seg * 32 + jj + e;
                *(unsigned*)(sm + ((n * 512 + 4 * p) ^ ((n & 7) << 4))) = packbf(av[e], cv[e]);
            }
        }
    }
    // wo -> bf16 (first 64 blocks, independent work)
    if (blockIdx.x < 64) {
        const int i = blockIdx.x * 512 + t;
        woB[i] = (short)f2b(wo[i]);
    }
    __syncthreads();

    // ---- compute: wave w owns n-tile w; 12 o-tiles; K=256 in 8 chunks ----
    bf16x8 xA[8];
#pragma unroll
    for (int kc = 0; kc < 8; ++kc) {
        const int n = w * 16 + lr;
        xA[kc] = *(const bf16x8*)(sm + ((n * 512 + (kc * 32 + lg * 8) * 2) ^ ((n & 7) << 4)));
    }
    f32x4 acc[12];
#pragma unroll
    for (int ot = 0; ot < 12; ++ot) {
        acc[ot] = (f32x4){0.f, 0.f, 0.f, 0.f};
        const short* wrow = wsB + (size_t)(ot * 16 + lr) * 256 + lg * 8;
#pragma unroll
        for (int kc = 0; kc < 8; ++kc) {
            bf16x8 wB = *(const bf16x8*)(wrow + kc * 32);
            acc[ot] = MFMA16(xA[kc], wB, acc[ot]);
        }
    }
    __syncthreads();   // xs dead; reuse LDS as raw[o=192][n=128] (swizzled)

#pragma unroll
    for (int ot = 0; ot < 12; ++ot) {
        const int o = ot * 16 + lr;
        const int n = w * 16 + lg * 4;
        const int base = o * 256 + n * 2;
        *(unsigned*)(sm + ((base)     ^ ((o & 7) << 4))) = packbf(acc[ot][0], acc[ot][1]);
        *(unsigned*)(sm + ((base + 4) ^ ((o & 7) << 4))) = packbf(acc[ot][2], acc[ot][3]);
    }
    __syncthreads();

    // ---- f store: fT[n][0..31] ----
    {
        const int n = t & 127, oq = t >> 7;     // oq 0..3
        unsigned pk[4];
#pragma unroll
        for (int v = 0; v < 4; ++v) {
            const int o0 = oq * 8 + v * 2;
            unsigned short b0 = *(unsigned short*)(sm + (((o0)     * 256 + n * 2) ^ (((o0)     & 7) << 4)));
            unsigned short b1 = *(unsigned short*)(sm + (((o0 + 1) * 256 + n * 2) ^ (((o0 + 1) & 7) << 4)));
            pk[v] = (unsigned)b0 | ((unsigned)b1 << 16);
        }
        *(uint4*)(fT + ((size_t)(b * N_ + nb + n)) * 32 + oq * 8) = make_uint4(pk[0], pk[1], pk[2], pk[3]);
    }

    // ---- 2x2 maxpool of rows 32..191 -> g (to pg LDS), h (to hM global) ----
    {
        const int j  = t & 31;          // pooled col
        const int ob = t >> 5;          // 0..15
#pragma unroll
        for (int i = 0; i < 10; ++i) {
            const int oo = ob + i * 16;             // 0..159
            const int ro = 32 + oo;
            const int base = ro * 256;
            const unsigned u0 = *(unsigned*)(sm + ((base + 4 * j)       ^ ((ro & 7) << 4)));
            const unsigned u1 = *(unsigned*)(sm + ((base + 128 + 4 * j) ^ ((ro & 7) << 4)));
            union { unsigned u; float f; } c0, c1, c2, c3;
            c0.u = u0 << 16; c1.u = u0 & 0xFFFF0000u;
            c2.u = u1 << 16; c3.u = u1 & 0xFFFF0000u;
            const float mx = fmaxf(fmaxf(c0.f, c1.f), fmaxf(c2.f, c3.f));
            if (oo < 32) {
                *(unsigned short*)(sm + 49664 + j * 68 + oo * 2) = f2b(mx);
            } else {
                hM[((size_t)(b * 128 + (oo - 32))) * M_ + mb + j] = (short)f2b(mx);
            }
        }
    }
    __syncthreads();
    // ---- g store from pg: gT[m][0..31] ----
    if (t < 128) {
        const int jm = t >> 2, q = t & 3;
        const char* pgb = sm + 49664 + jm * 68 + q * 16;
        unsigned v0 = *(unsigned*)(pgb + 0), v1 = *(unsigned*)(pgb + 4),
                 v2 = *(unsigned*)(pgb + 8), v3 = *(unsigned*)(pgb + 12);
        *(uint4*)(gT + ((size_t)(b * M_ + mb + jm)) * 32 + q * 8) = make_uint4(v0, v1, v2, v3);
    }
}

// ---------------- k2: flash attention (swapped QK^T) + wo epilogue ------------
__global__ __launch_bounds__(256, 2)
void k2_attn(const short* __restrict__ fT, const short* __restrict__ gT,
             const short* __restrict__ hM, const short* __restrict__ woB,
             const float* __restrict__ x, const float* __restrict__ gam,
             float* __restrict__ out) {
    __shared__ __align__(64) char sm[49152];   // [0,32768) hs | [32768,49152) P_lds ; OT unions [0,16384)
    const int t    = threadIdx.x;
    const int lane = t & 63;
    const int w    = t >> 6;            // wave 0..3, owns n-sub w*16
    const int lr   = lane & 15, lg = lane >> 4;
    const int b    = blockIdx.x >> 6;
    const int nt   = blockIdx.x & 63;
    const int n0   = nt * 64;

    const f32x4 z4 = (f32x4){0.f, 0.f, 0.f, 0.f};

    // hoisted f B-fragment (this wave's 16 n-columns, full K=32)
    const bf16x8 fB = *(const bf16x8*)(fT + ((size_t)(b * N_ + n0 + w * 16 + lr)) * 32 + lg * 8);

    f32x4 acc[8];
#pragma unroll
    for (int j = 0; j < 8; ++j) acc[j] = z4;
    float M = -1e30f, Lp = 0.f;

    const int pbase = 32768 + w * 4096;
    const int swz   = (lr & 7) << 4;

    for (int mt8 = 0; mt8 < 8; ++mt8) {
        const int m0 = mt8 * 128;
        __syncthreads();
        // stage hs[c=128][m=128] bf16 swizzled (PV B-operand)
        {
            bf16x8 hv[8];
#pragma unroll
            for (int i = 0; i < 8; ++i) {
                const int slot = t + i * 256, c = slot >> 4, p = slot & 15;
                hv[i] = *(const bf16x8*)(hM + ((size_t)(b * 128 + c)) * M_ + m0 + p * 8);
            }
#pragma unroll
            for (int i = 0; i < 8; ++i) {
                const int slot = t + i * 256, c = slot >> 4, p = slot & 15;
                *(bf16x8*)(sm + ((c * 256 + p * 16) ^ ((c & 7) << 4))) = hv[i];
            }
        }
        // S^T[m][n] via MFMA (A = gT rows m, direct global; B = fB)
        f32x4 s[8];
#pragma unroll
        for (int mt = 0; mt < 8; ++mt) {
            bf16x8 gA = *(const bf16x8*)(gT + ((size_t)(b * M_ + m0 + mt * 16 + lr)) * 32 + lg * 8);
            s[mt] = MFMA16(gA, fB, z4);
        }
        // online softmax over m (in-lane 32 + cross-group shfl)
        float pm = -1e30f;
#pragma unroll
        for (int mt = 0; mt < 8; ++mt)
            pm = fmaxf(pm, fmaxf(fmaxf(s[mt][0], s[mt][1]), fmaxf(s[mt][2], s[mt][3])));
        pm = fmaxf(pm, __shfl_xor(pm, 16));
        pm = fmaxf(pm, __shfl_xor(pm, 32));
        const float Mn = fmaxf(M, pm);
        const float scale = __expf(M - Mn);
        M = Mn;
        float ps = 0.f;
#pragma unroll
        for (int mt = 0; mt < 8; ++mt) {
#pragma unroll
            for (int r = 0; r < 4; ++r) {
                const float p = __expf(s[mt][r] - Mn);
                s[mt][r] = p; ps += p;
            }
        }
        Lp = Lp * scale + ps;
        // P -> own-wave LDS region [n=16][m=128] bf16 swizzled
#pragma unroll
        for (int mt = 0; mt < 8; ++mt) {
            const int base = lr * 256 + (mt * 16 + lg * 4) * 2;
            *(unsigned*)(sm + pbase + ((base)     ^ swz)) = packbf(s[mt][0], s[mt][1]);
            *(unsigned*)(sm + pbase + ((base + 4) ^ swz)) = packbf(s[mt][2], s[mt][3]);
        }
        // rescale running accumulator (scale lives at lane lr == n)
        const float sc0 = __shfl(scale, lg * 4 + 0);
        const float sc1 = __shfl(scale, lg * 4 + 1);
        const float sc2 = __shfl(scale, lg * 4 + 2);
        const float sc3 = __shfl(scale, lg * 4 + 3);
#pragma unroll
        for (int cj = 0; cj < 8; ++cj) {
            acc[cj][0] *= sc0; acc[cj][1] *= sc1; acc[cj][2] *= sc2; acc[cj][3] *= sc3;
        }
        __syncthreads();
        // PV: acc[n][c] += P[n][m] * h[m][c]
#pragma unroll
        for (int kc = 0; kc < 4; ++kc) {
            const bf16x8 pA = *(const bf16x8*)(sm + pbase + ((lr * 256 + (kc * 32 + lg * 8) * 2) ^ swz));
#pragma unroll
            for (int cj = 0; cj < 8; ++cj) {
                const int c = cj * 16 + lr;
                const bf16x8 hB = *(const bf16x8*)(sm + ((c * 256 + (kc * 32 + lg * 8) * 2) ^ ((c & 7) << 4)));
                acc[cj] = MFMA16(pA, hB, acc[cj]);
            }
        }
    }
    // finalize 1/L
    Lp += __shfl_xor(Lp, 16);
    Lp += __shfl_xor(Lp, 32);
    const float inv = 1.f / Lp;
    const float iv0 = __shfl(inv, lg * 4 + 0), iv1 = __shfl(inv, lg * 4 + 1),
                iv2 = __shfl(inv, lg * 4 + 2), iv3 = __shfl(inv, lg * 4 + 3);
    __syncthreads();   // hs dead
    // OT[n=64][c=128] bf16 swizzled at base 0
#pragma unroll
    for (int cj = 0; cj < 8; ++cj) {
        const int c = cj * 16 + lr;
        const float vv[4] = {acc[cj][0] * iv0, acc[cj][1] * iv1, acc[cj][2] * iv2, acc[cj][3] * iv3};
#pragma unroll
        for (int r = 0; r < 4; ++r) {
            const int n = w * 16 + lg * 4 + r;
            *(unsigned short*)(sm + ((n * 256 + c * 2) ^ ((n & 7) << 4))) = f2b(vv[r]);
        }
    }
    __syncthreads();
    // epilogue: out[oc][n] = gamma * (wo . O^T) + x
    const float gamma = gam[0];
#pragma unroll
    for (int ti = 0; ti < 4; ++ti) {
        const int oc0 = w * 64 + ti * 16;
        bf16x8 wA[4];
#pragma unroll
        for (int kc = 0; kc < 4; ++kc)
            wA[kc] = *(const bf16x8*)(woB + (size_t)(oc0 + lr) * 128 + kc * 32 + lg * 8);
#pragma unroll
        for (int ni = 0; ni < 4; ++ni) {
            f32x4 e = z4;
#pragma unroll
            for (int kc = 0; kc < 4; ++kc) {
                const int n = ni * 16 + lr;
                const bf16x8 oB = *(const bf16x8*)(sm + ((n * 256 + (kc * 32 + lg * 8) * 2) ^ swz));
                e = MFMA16(wA[kc], oB, e);
            }
#pragma unroll
            for (int r = 0; r < 4; ++r) {
                const int oc = oc0 + lg * 4 + r;
                const size_t idx = ((size_t)(b * 256 + oc)) * N_ + n0 + ni * 16 + lr;
                out[idx] = gamma * e[r] + x[idx];
            }
        }
    }
}

extern "C" void kernel_launch(void* const* d_in, const int* in_sizes, int n_in,
                              void* d_out, int out_size, void* d_ws, size_t ws_size,
                              hipStream_t stream) {
    (void)in_sizes; (void)n_in; (void)out_size; (void)ws_size;
    const float* x   = (const float*)d_in[0];
    const float* wf  = (const float*)d_in[1];
    const float* wg  = (const float*)d_in[2];
    const float* wh  = (const float*)d_in[3];
    const float* wo  = (const float*)d_in[4];
    const float* gam = (const float*)d_in[5];
    float* out = (float*)d_out;

    short* ws  = (short*)d_ws;
    short* wsB = ws;                       // 49152
    short* woB = ws + 49152;               // 32768
    short* fT  = ws + 81920;               // 16*4096*32 = 2097152
    short* gT  = ws + 2179072;             // 16*1024*32 = 524288
    short* hM  = ws + 2703360;             // 16*128*1024 = 2097152

    k0_wcvt<<<dim3(48),   dim3(256), 0, stream>>>(wf, wg, wh, wsB);
    k1_proj<<<dim3(512),  dim3(512), 0, stream>>>(x, wsB, wo, fT, gT, hM, woB);
    k2_attn<<<dim3(1024), dim3(256), 0, stream>>>(fT, gT, hM, woB, x, gam, out);
}